// Round 1
// baseline (934.539 us; speedup 1.0000x reference)
//
#include <hip/hip_runtime.h>

typedef unsigned int u32;
typedef unsigned short u16;
typedef __attribute__((ext_vector_type(8))) __bf16 bf16x8;
typedef __attribute__((ext_vector_type(4))) float f32x4;

__device__ __forceinline__ u16 f2bf(float f){
  u32 u = __builtin_bit_cast(u32, f);
  return (u16)((u + 0x7FFFu + ((u >> 16) & 1u)) >> 16);
}
__device__ __forceinline__ float bf2f(u16 h){
  u32 u = ((u32)h) << 16;
  return __builtin_bit_cast(float, u);
}

// ---------- weight transpose-cast: out[n][k] = W[k][n] * scale (1024x1024) ----------
__global__ void wcast(const float* __restrict__ W, float scale, u16* __restrict__ out){
  __shared__ float t[32][33];
  int bx = blockIdx.x * 32, by = blockIdx.y * 32;
  int tx = threadIdx.x, ty = threadIdx.y;
  #pragma unroll
  for (int i = 0; i < 32; i += 8) t[ty + i][tx] = W[(size_t)(bx + ty + i) * 1024 + by + tx];
  __syncthreads();
  #pragma unroll
  for (int i = 0; i < 32; i += 8)
    out[(size_t)(by + ty + i) * 1024 + bx + tx] = f2bf(scale * t[tx][ty + i]);
}

// ---------- GEMM: C[M][N] = A[M][K] @ B[N][K]^T (+bias), bf16 MFMA ----------
// Tile 128x128, BK=64, 256 threads (4 waves, 2x2), 16x16x32 MFMA, 4x4 frags/wave.
// LDS layout: [row][chunk] with chunk (16B) XOR-swizzled by (row&7) -> conflict-free b128.

template<bool F32>
__device__ __forceinline__ void stage_tile(const void* src, int ld, int k0, u16* lds, int tid){
  #pragma unroll
  for (int i = 0; i < 4; i++){
    int t = i * 256 + tid;
    int row = t >> 3;        // 8 chunks (of 8 elems) per 64-elem row
    int cpos = t & 7;
    uint4 d;
    if constexpr (F32) {
      const float* g = (const float*)src + (size_t)row * ld + k0 + cpos * 8;
      float4 f0 = ((const float4*)g)[0];
      float4 f1 = ((const float4*)g)[1];
      union { uint4 u4; u16 h[8]; } uu;
      uu.h[0]=f2bf(f0.x); uu.h[1]=f2bf(f0.y); uu.h[2]=f2bf(f0.z); uu.h[3]=f2bf(f0.w);
      uu.h[4]=f2bf(f1.x); uu.h[5]=f2bf(f1.y); uu.h[6]=f2bf(f1.z); uu.h[7]=f2bf(f1.w);
      d = uu.u4;
    } else {
      const u16* g = (const u16*)src + (size_t)row * ld + k0 + cpos * 8;
      d = *(const uint4*)g;
    }
    *(uint4*)((char*)lds + row * 128 + ((cpos ^ (row & 7)) * 16)) = d;
  }
}

__device__ __forceinline__ bf16x8 rdfrag(const u16* lds, int row, int c){
  uint4 u = *(const uint4*)((const char*)lds + row * 128 + ((c ^ (row & 7)) * 16));
  return __builtin_bit_cast(bf16x8, u);
}

template<int AF32, int BF32, int BIAS, int OUTF32>
__global__ __launch_bounds__(256, 2) void gemm(
    const void* __restrict__ A, const void* __restrict__ B, void* __restrict__ C,
    const float* __restrict__ bias, float bscale,
    int K, long long sA, long long sB, long long sC,
    int lda, int ldb, int ldc)
{
  __shared__ u16 lA[128 * 64];
  __shared__ u16 lB[128 * 64];
  int tid = threadIdx.x;
  int lane = tid & 63, wave = tid >> 6;
  int wr = wave >> 1, wc = wave & 1;
  int l15 = lane & 15, l4 = lane >> 4;
  int row0 = blockIdx.x * 128, col0 = blockIdx.y * 128;
  long long zb = blockIdx.z;

  const void* Ab = AF32 ? (const void*)((const float*)A + zb * sA + (size_t)row0 * lda)
                        : (const void*)((const u16*)A + zb * sA + (size_t)row0 * lda);
  const void* Bb = BF32 ? (const void*)((const float*)B + zb * sB + (size_t)col0 * ldb)
                        : (const void*)((const u16*)B + zb * sB + (size_t)col0 * ldb);

  f32x4 acc[4][4] = {};

  for (int k0 = 0; k0 < K; k0 += 64){
    stage_tile<AF32 != 0>(Ab, lda, k0, lA, tid);
    stage_tile<BF32 != 0>(Bb, ldb, k0, lB, tid);
    __syncthreads();
    #pragma unroll
    for (int ks = 0; ks < 2; ks++){
      bf16x8 af[4], bfr[4];
      #pragma unroll
      for (int m = 0; m < 4; m++) af[m] = rdfrag(lA, wr * 64 + m * 16 + l15, ks * 4 + l4);
      #pragma unroll
      for (int n = 0; n < 4; n++) bfr[n] = rdfrag(lB, wc * 64 + n * 16 + l15, ks * 4 + l4);
      #pragma unroll
      for (int m = 0; m < 4; m++)
        #pragma unroll
        for (int n = 0; n < 4; n++)
          acc[m][n] = __builtin_amdgcn_mfma_f32_16x16x32_bf16(af[m], bfr[n], acc[m][n], 0, 0, 0);
    }
    __syncthreads();
  }

  #pragma unroll
  for (int m = 0; m < 4; m++){
    #pragma unroll
    for (int n = 0; n < 4; n++){
      int gr0 = row0 + wr * 64 + m * 16 + l4 * 4;
      int gc  = col0 + wc * 64 + n * 16 + l15;
      #pragma unroll
      for (int j = 0; j < 4; j++){
        float vv = acc[m][n][j];
        int gr = gr0 + j;
        if (BIAS == 1) vv += bscale * bias[gc];
        if (BIAS == 2) vv += bscale * bias[gr];
        if (OUTF32) ((float*)C)[zb * sC + (size_t)gr * ldc + gc] = vv;
        else        ((u16*) C)[zb * sC + (size_t)gr * ldc + gc] = f2bf(vv);
      }
    }
  }
}

// ---------- row softmax, in-place on bf16 S rows of length 2048 ----------
__global__ __launch_bounds__(256) void softmax_rows(u16* __restrict__ S){
  __shared__ float red[8];
  size_t row = blockIdx.x;
  uint4* p = (uint4*)(S + row * 2048);
  int tid = threadIdx.x;
  int lane = tid & 63, wave = tid >> 6;
  union { uint4 u4; u16 h[8]; } uu;
  uu.u4 = p[tid];
  float v[8];
  float m = -1e30f;
  #pragma unroll
  for (int j = 0; j < 8; j++){ v[j] = bf2f(uu.h[j]); m = fmaxf(m, v[j]); }
  #pragma unroll
  for (int o = 32; o; o >>= 1) m = fmaxf(m, __shfl_xor(m, o));
  if (lane == 0) red[wave] = m;
  __syncthreads();
  m = fmaxf(fmaxf(red[0], red[1]), fmaxf(red[2], red[3]));
  float s = 0.f;
  #pragma unroll
  for (int j = 0; j < 8; j++){ v[j] = __expf(v[j] - m); s += v[j]; }
  #pragma unroll
  for (int o = 32; o; o >>= 1) s += __shfl_xor(s, o);
  if (lane == 0) red[4 + wave] = s;
  __syncthreads();
  s = red[4] + red[5] + red[6] + red[7];
  float inv = 1.f / s;
  #pragma unroll
  for (int j = 0; j < 8; j++) uu.h[j] = f2bf(v[j] * inv);
  p[tid] = uu.u4;
}

extern "C" void kernel_launch(void* const* d_in, const int* in_sizes, int n_in,
                              void* d_out, int out_size, void* d_ws, size_t ws_size,
                              hipStream_t stream){
  const float* q  = (const float*)d_in[0];
  const float* k  = (const float*)d_in[1];
  const float* v  = (const float*)d_in[2];
  const float* Wq = (const float*)d_in[3];
  const float* bq = (const float*)d_in[4];
  const float* Wk = (const float*)d_in[5];
  const float* bk = (const float*)d_in[6];
  const float* Wv = (const float*)d_in[7];
  const float* bv = (const float*)d_in[8];
  const float* Wo = (const float*)d_in[9];
  const float* bo = (const float*)d_in[10];

  char* ws = (char*)d_ws;
  const size_t MB = (size_t)1 << 20;
  u16* Wqt = (u16*)(ws + 0 * MB);    // 2 MB each
  u16* Wkt = (u16*)(ws + 2 * MB);
  u16* Wvt = (u16*)(ws + 4 * MB);
  u16* Wot = (u16*)(ws + 6 * MB);
  u16* Qp  = (u16*)(ws + 8 * MB);    // [32768][1024] bf16, 64 MB
  u16* Kp  = (u16*)(ws + 72 * MB);   // [32768][1024] bf16, 64 MB
  u16* Vt  = (u16*)(ws + 136 * MB);  // [16][1024][2048] bf16, 64 MB
  u16* S   = (u16*)(ws + 200 * MB);  // [16][2048][2048] bf16, 128 MB (P in-place)
  u16* O   = (u16*)(ws + 328 * MB);  // [32768][1024] bf16, 64 MB
  float* out = (float*)d_out;

  dim3 wb(32, 8);
  wcast<<<dim3(32, 32), wb, 0, stream>>>(Wq, 1.f / 32.f, Wqt);  // fold 1/sqrt(D)
  wcast<<<dim3(32, 32), wb, 0, stream>>>(Wk, 1.f, Wkt);
  wcast<<<dim3(32, 32), wb, 0, stream>>>(Wv, 1.f, Wvt);
  wcast<<<dim3(32, 32), wb, 0, stream>>>(Wo, 1.f, Wot);

  // Q' = (q @ Wq + bq)/32  -> Qp bf16
  gemm<1,0,1,0><<<dim3(256, 8, 1), 256, 0, stream>>>(q, Wqt, Qp, bq, 1.f/32.f,
      1024, 0, 0, 0, 1024, 1024, 1024);
  // K' = k @ Wk + bk -> Kp bf16
  gemm<1,0,1,0><<<dim3(256, 8, 1), 256, 0, stream>>>(k, Wkt, Kp, bk, 1.f,
      1024, 0, 0, 0, 1024, 1024, 1024);
  // Vt[b][d][kv] = (v @ Wv + bv)^T : A=Wvt[1024][1024], B=v[b][2048][1024], bias per-row(d)
  gemm<0,1,2,0><<<dim3(8, 16, 16), 256, 0, stream>>>(Wvt, v, Vt, bv, 1.f,
      1024, 0, 2048LL * 1024, 1024LL * 2048, 1024, 1024, 2048);
  // S[b] = Qp[b] @ Kp[b]^T
  gemm<0,0,0,0><<<dim3(16, 16, 16), 256, 0, stream>>>(Qp, Kp, S, nullptr, 0.f,
      1024, 2048LL * 1024, 2048LL * 1024, 2048LL * 2048, 1024, 1024, 2048);
  // P = softmax(S) in place
  softmax_rows<<<dim3(32768), 256, 0, stream>>>(S);
  // O[b] = P[b] @ Vt[b]^T
  gemm<0,0,0,0><<<dim3(16, 8, 16), 256, 0, stream>>>(S, Vt, O, nullptr, 0.f,
      2048, 2048LL * 2048, 1024LL * 2048, 2048LL * 1024, 2048, 2048, 1024);
  // out = O @ Wo + bo (fp32 out)
  gemm<0,0,1,1><<<dim3(256, 8, 1), 256, 0, stream>>>(O, Wot, out, bo, 1.f,
      1024, 0, 0, 0, 1024, 1024, 1024);
}

// Round 2
// 727.345 us; speedup vs baseline: 1.2849x; 1.2849x over previous
//
#include <hip/hip_runtime.h>

typedef unsigned int u32;
typedef unsigned short u16;
typedef __attribute__((ext_vector_type(8))) __bf16 bf16x8;
typedef __attribute__((ext_vector_type(4))) float f32x4;

typedef __attribute__((address_space(1))) void as1_void;
typedef __attribute__((address_space(3))) void as3_void;

__device__ __forceinline__ u16 f2bf(float f){
  u32 u = __builtin_bit_cast(u32, f);
  return (u16)((u + 0x7FFFu + ((u >> 16) & 1u)) >> 16);
}
__device__ __forceinline__ float bf2f(u16 h){
  u32 u = ((u32)h) << 16;
  return __builtin_bit_cast(float, u);
}

__device__ __forceinline__ void gload16(const void* g, void* l){
  __builtin_amdgcn_global_load_lds((as1_void*)(unsigned long long)g, (as3_void*)l, 16, 0, 0);
}
__device__ __forceinline__ bf16x8 ldfrag(const char* p){
  return __builtin_bit_cast(bf16x8, *(const uint4*)p);
}

// ---------- weight transpose-cast: out[n][k] = W[k][n] * scale (1024x1024) ----------
__global__ void wcast(const float* __restrict__ W, float scale, u16* __restrict__ out){
  __shared__ float t[32][33];
  int bx = blockIdx.x * 32, by = blockIdx.y * 32;
  int tx = threadIdx.x, ty = threadIdx.y;
  #pragma unroll
  for (int i = 0; i < 32; i += 8) t[ty + i][tx] = W[(size_t)(bx + ty + i) * 1024 + by + tx];
  __syncthreads();
  #pragma unroll
  for (int i = 0; i < 32; i += 8)
    out[(size_t)(by + ty + i) * 1024 + bx + tx] = f2bf(scale * t[tx][ty + i]);
}

// ---------- fp32 -> bf16 cast, 8 elems/thread ----------
__global__ __launch_bounds__(256) void castbf(const float* __restrict__ in, u16* __restrict__ out, int n8){
  int stride = gridDim.x * blockDim.x;
  for (int i = blockIdx.x * blockDim.x + threadIdx.x; i < n8; i += stride){
    const float4* p = (const float4*)(in + (size_t)i * 8);
    float4 f0 = p[0], f1 = p[1];
    union { uint4 u; u16 h[8]; } uu;
    uu.h[0]=f2bf(f0.x); uu.h[1]=f2bf(f0.y); uu.h[2]=f2bf(f0.z); uu.h[3]=f2bf(f0.w);
    uu.h[4]=f2bf(f1.x); uu.h[5]=f2bf(f1.y); uu.h[6]=f2bf(f1.z); uu.h[7]=f2bf(f1.w);
    ((uint4*)out)[i] = uu.u;
  }
}

// ---------- row softmax, in-place on bf16 S rows of length 2048 ----------
__global__ __launch_bounds__(256) void softmax_rows(u16* __restrict__ S){
  __shared__ float red[8];
  size_t row = blockIdx.x;
  uint4* p = (uint4*)(S + row * 2048);
  int tid = threadIdx.x;
  int lane = tid & 63, wave = tid >> 6;
  union { uint4 u4; u16 h[8]; } uu;
  uu.u4 = p[tid];
  float v[8];
  float m = -1e30f;
  #pragma unroll
  for (int j = 0; j < 8; j++){ v[j] = bf2f(uu.h[j]); m = fmaxf(m, v[j]); }
  #pragma unroll
  for (int o = 32; o; o >>= 1) m = fmaxf(m, __shfl_xor(m, o));
  if (lane == 0) red[wave] = m;
  __syncthreads();
  m = fmaxf(fmaxf(red[0], red[1]), fmaxf(red[2], red[3]));
  float s = 0.f;
  #pragma unroll
  for (int j = 0; j < 8; j++){ v[j] = __expf(v[j] - m); s += v[j]; }
  #pragma unroll
  for (int o = 32; o; o >>= 1) s += __shfl_xor(s, o);
  if (lane == 0) red[4 + wave] = s;
  __syncthreads();
  s = red[4] + red[5] + red[6] + red[7];
  float inv = 1.f / s;
  #pragma unroll
  for (int j = 0; j < 8; j++) uu.h[j] = f2bf(v[j] * inv);
  p[tid] = uu.u4;
}

// ---------- 256x256 8-phase GEMM: C[M][N] = A[M][K] @ B[N][K]^T (+bias) ----------
// 512 threads = 8 waves (2 row x 4 col), BK=64, dbuf LDS 128 KiB, global_load_lds,
// XOR-swizzled ds_read_b128, counted vmcnt(6), setprio around MFMA clusters.

template<int MO, int N0>
__device__ __forceinline__ void phase_mfma(f32x4 (&acc)[8][4], bf16x8 (&a)[4][2], bf16x8 (&b)[4][2]){
  __builtin_amdgcn_s_setprio(1);
  #pragma unroll
  for (int ks = 0; ks < 2; ks++)
    #pragma unroll
    for (int mm = 0; mm < 4; mm++)
      #pragma unroll
      for (int nn = 0; nn < 2; nn++)
        acc[MO + mm][N0 + nn] = __builtin_amdgcn_mfma_f32_16x16x32_bf16(
            a[mm][ks], b[N0 + nn][ks], acc[MO + mm][N0 + nn], 0, 0, 0);
  __builtin_amdgcn_s_setprio(0);
}

template<int BIAS, int OUTF32>
__global__ __launch_bounds__(512, 2) void gemm8(
    const u16* __restrict__ A, const u16* __restrict__ B, void* __restrict__ C,
    const float* __restrict__ bias, float bscale, int K,
    long long sA, long long sB, long long sC,
    int lda, int ldb, int ldc, int gx, int gxy)
{
  __shared__ u16 sm[2][2][16384];   // [buf][A/B][256 rows x 64 cols] = 128 KiB
  char* smb = (char*)&sm[0][0][0];

  int tid = threadIdx.x;
  int lane = tid & 63, wave = tid >> 6;
  int wr = wave >> 2, wc = wave & 3;
  int l15 = lane & 15, l4 = lane >> 4;

  // XCD-aware bijective block swizzle (all grids divisible by 8)
  int nwg = gxy * gridDim.z;
  int lin = blockIdx.x + gx * blockIdx.y + gxy * blockIdx.z;
  int cpx = nwg >> 3;
  int swz = (lin & 7) * cpx + (lin >> 3);
  int tz = swz / gxy; int rem = swz - tz * gxy;
  int ty = rem / gx;  int tx = rem - ty * gx;
  long long zb = tz;
  int row0 = tx * 256, col0 = ty * 256;

  const char* Aglob = (const char*)(A + zb * sA + (size_t)row0 * lda);
  const char* Bglob = (const char*)(B + zb * sB + (size_t)col0 * ldb);

  // staging addressing: issue i covers rows [i*64, i*64+64), 16B per lane
  int r = tid >> 3, cl = tid & 7;
  int ldsb = r * 128 + cl * 16;
  u32 aoff[4], boff[4];
  #pragma unroll
  for (int i = 0; i < 4; i++){
    int row = i * 64 + r;
    int ksw = (cl ^ (r & 7)) * 8;            // inverse-swizzled global k-chunk
    aoff[i] = (u32)(((u32)row * (u32)lda + (u32)ksw) * 2u);
    boff[i] = (u32)(((u32)row * (u32)ldb + (u32)ksw) * 2u);
  }
  // fragment-read addressing (swizzled)
  u32 ardo[2], brdo[2];
  #pragma unroll
  for (int ks = 0; ks < 2; ks++){
    u32 sw = (u32)(((ks * 4 + l4) ^ (l15 & 7)) * 16);
    ardo[ks] = (u32)(wr * 16384 + l15 * 128) + sw;
    brdo[ks] = (u32)(wc * 8192 + l15 * 128) + sw;
  }

#define STA(i, tau, bb) gload16(Aglob + aoff[i] + (size_t)(tau) * 128, smb + (bb) * 65536 + (i) * 8192 + ldsb)
#define STB(i, tau, bb) gload16(Bglob + boff[i] + (size_t)(tau) * 128, smb + (bb) * 65536 + 32768 + (i) * 8192 + ldsb)

  int NT = K >> 6;

  // prologue: tile0 (4 halves), then tile1 minus A_hi (3 halves); 3 halves left in flight
  STA(0, 0, 0); STA(2, 0, 0);
  STB(0, 0, 0); STB(1, 0, 0);
  STB(2, 0, 0); STB(3, 0, 0);
  STA(1, 0, 0); STA(3, 0, 0);
  STA(0, 1, 1); STA(2, 1, 1);
  STB(0, 1, 1); STB(1, 1, 1);
  STB(2, 1, 1); STB(3, 1, 1);
  asm volatile("s_waitcnt vmcnt(6)" ::: "memory");
  __builtin_amdgcn_s_barrier();

  f32x4 acc[8][4] = {};
  bf16x8 a[4][2], b[4][2];

  for (int t = 0; t < NT; t++){
    int cur = t & 1;
    const char* Abase = smb + cur * 65536;
    const char* Bbase = Abase + 32768;

    // ---- P0: read A_lo + B n0-1; stage A_hi(t+1) -> other buf ----
    #pragma unroll
    for (int mm = 0; mm < 4; mm++)
      #pragma unroll
      for (int ks = 0; ks < 2; ks++)
        a[mm][ks] = ldfrag(Abase + mm * 2048 + ardo[ks]);
    #pragma unroll
    for (int nn = 0; nn < 2; nn++)
      #pragma unroll
      for (int ks = 0; ks < 2; ks++)
        b[nn][ks] = ldfrag(Bbase + nn * 2048 + brdo[ks]);
    if (t + 1 < NT){ STA(1, t + 1, cur ^ 1); STA(3, t + 1, cur ^ 1); }
    __builtin_amdgcn_s_barrier();
    phase_mfma<0, 0>(acc, a, b);
    __builtin_amdgcn_s_barrier();

    // ---- P1: read B n2-3; stage A_lo(t+2) -> this buf ----
    #pragma unroll
    for (int nn = 2; nn < 4; nn++)
      #pragma unroll
      for (int ks = 0; ks < 2; ks++)
        b[nn][ks] = ldfrag(Bbase + nn * 2048 + brdo[ks]);
    if (t + 2 < NT){ STA(0, t + 2, cur); STA(2, t + 2, cur); }
    __builtin_amdgcn_s_barrier();
    phase_mfma<0, 2>(acc, a, b);
    __builtin_amdgcn_s_barrier();

    // ---- P2: read A_hi; stage B_h0(t+2) ----
    #pragma unroll
    for (int mm = 0; mm < 4; mm++)
      #pragma unroll
      for (int ks = 0; ks < 2; ks++)
        a[mm][ks] = ldfrag(Abase + (4 + mm) * 2048 + ardo[ks]);
    if (t + 2 < NT){ STB(0, t + 2, cur); STB(1, t + 2, cur); }
    __builtin_amdgcn_s_barrier();
    phase_mfma<4, 0>(acc, a, b);
    __builtin_amdgcn_s_barrier();

    // ---- P3: stage B_h1(t+2); counted vmcnt ----
    if (t + 2 < NT){ STB(2, t + 2, cur); STB(3, t + 2, cur); }
    if (t < NT - 2) asm volatile("s_waitcnt vmcnt(6)" ::: "memory");
    else            asm volatile("s_waitcnt vmcnt(0)" ::: "memory");
    __builtin_amdgcn_s_barrier();
    phase_mfma<4, 2>(acc, a, b);
    __builtin_amdgcn_s_barrier();
  }
#undef STA
#undef STB

  // epilogue
  #pragma unroll
  for (int m = 0; m < 8; m++){
    #pragma unroll
    for (int n = 0; n < 4; n++){
      int gr0 = row0 + wr * 128 + m * 16 + l4 * 4;
      int gc  = col0 + wc * 64 + n * 16 + l15;
      float bcol = (BIAS == 1) ? bscale * bias[gc] : 0.f;
      #pragma unroll
      for (int j = 0; j < 4; j++){
        float vv = acc[m][n][j];
        int gr = gr0 + j;
        if (BIAS == 1) vv += bcol;
        if (BIAS == 2) vv += bscale * bias[gr];
        if (OUTF32) ((float*)C)[zb * sC + (size_t)gr * ldc + gc] = vv;
        else        ((u16*) C)[zb * sC + (size_t)gr * ldc + gc] = f2bf(vv);
      }
    }
  }
}

extern "C" void kernel_launch(void* const* d_in, const int* in_sizes, int n_in,
                              void* d_out, int out_size, void* d_ws, size_t ws_size,
                              hipStream_t stream){
  const float* q  = (const float*)d_in[0];
  const float* k  = (const float*)d_in[1];
  const float* v  = (const float*)d_in[2];
  const float* Wq = (const float*)d_in[3];
  const float* bq = (const float*)d_in[4];
  const float* Wk = (const float*)d_in[5];
  const float* bk = (const float*)d_in[6];
  const float* Wv = (const float*)d_in[7];
  const float* bv = (const float*)d_in[8];
  const float* Wo = (const float*)d_in[9];
  const float* bo = (const float*)d_in[10];

  char* ws = (char*)d_ws;
  const size_t MB = (size_t)1 << 20;
  u16* Wqt = (u16*)(ws + 0 * MB);
  u16* Wkt = (u16*)(ws + 2 * MB);
  u16* Wvt = (u16*)(ws + 4 * MB);
  u16* Wot = (u16*)(ws + 6 * MB);
  u16* Qp  = (u16*)(ws + 8 * MB);    // [32768][1024] bf16
  u16* Kp  = (u16*)(ws + 72 * MB);   // [32768][1024] bf16
  u16* Vt  = (u16*)(ws + 136 * MB);  // [16][1024][2048] bf16
  u16* S   = (u16*)(ws + 200 * MB);  // [16][2048][2048] bf16 (P in-place)
  u16* O   = (u16*)(ws + 328 * MB);  // [32768][1024] bf16
  u16* X   = (u16*)(ws + 200 * MB);  // 64 MB staging for bf16 q/k/v (dead before S written)
  float* out = (float*)d_out;

  dim3 wb(32, 8);
  wcast<<<dim3(32, 32), wb, 0, stream>>>(Wq, 1.f / 32.f, Wqt);  // fold 1/sqrt(D)
  wcast<<<dim3(32, 32), wb, 0, stream>>>(Wk, 1.f, Wkt);
  wcast<<<dim3(32, 32), wb, 0, stream>>>(Wv, 1.f, Wvt);
  wcast<<<dim3(32, 32), wb, 0, stream>>>(Wo, 1.f, Wot);

  const int n8 = 16 * 2048 * 1024 / 8;

  // Q' = (q @ Wq + bq)/32
  castbf<<<dim3(2048), 256, 0, stream>>>(q, X, n8);
  gemm8<1,0><<<dim3(128, 4, 1), 512, 0, stream>>>(X, Wqt, Qp, bq, 1.f/32.f,
      1024, 0, 0, 0, 1024, 1024, 1024, 128, 512);
  // K' = k @ Wk + bk
  castbf<<<dim3(2048), 256, 0, stream>>>(k, X, n8);
  gemm8<1,0><<<dim3(128, 4, 1), 512, 0, stream>>>(X, Wkt, Kp, bk, 1.f,
      1024, 0, 0, 0, 1024, 1024, 1024, 128, 512);
  // Vt[b][d][kv] = (v @ Wv + bv)^T : A=Wvt[d][k], B=vb[b][kv][k], bias per-row(d)
  castbf<<<dim3(2048), 256, 0, stream>>>(v, X, n8);
  gemm8<2,0><<<dim3(4, 8, 16), 512, 0, stream>>>(Wvt, X, Vt, bv, 1.f,
      1024, 0, 2048LL * 1024, 1024LL * 2048, 1024, 1024, 2048, 4, 32);
  // S[b] = Qp[b] @ Kp[b]^T   (overwrites X region; X dead)
  gemm8<0,0><<<dim3(8, 8, 16), 512, 0, stream>>>(Qp, Kp, S, nullptr, 0.f,
      1024, 2048LL * 1024, 2048LL * 1024, 2048LL * 2048, 1024, 1024, 2048, 8, 64);
  // P = softmax(S) in place
  softmax_rows<<<dim3(32768), 256, 0, stream>>>(S);
  // O[b] = P[b] @ Vt[b]^T
  gemm8<0,0><<<dim3(8, 4, 16), 512, 0, stream>>>(S, Vt, O, nullptr, 0.f,
      2048, 2048LL * 2048, 1024LL * 2048, 2048LL * 1024, 2048, 2048, 1024, 8, 32);
  // out = O @ Wo + bo (fp32 out)
  gemm8<1,1><<<dim3(128, 4, 1), 512, 0, stream>>>(O, Wot, out, bo, 1.f,
      1024, 0, 0, 0, 1024, 1024, 1024, 128, 512);
}